// Round 5
// baseline (3801.410 us; speedup 1.0000x reference)
//
#include <hip/hip_runtime.h>
#include <math.h>

#define NEG_INF (-1e9f)
#define EPS 1e-5f

// ---------------- detect sparse_mask storage: int32 (0/1) vs packed bytes ----------------
__global__ void detect_mask_kernel(const unsigned int* __restrict__ sm, int* __restrict__ flag) {
    __shared__ int bad;
    if (threadIdx.x == 0) bad = 0;
    __syncthreads();
    for (int i = threadIdx.x; i < 4096; i += 256) {
        if (sm[i] > 1u) bad = 1;   // impossible for int32 bool storage
    }
    __syncthreads();
    if (threadIdx.x == 0) *flag = bad;   // 1 -> byte storage, 0 -> int32 storage
}

// ---------------- transpose: dst[c*R + r] = src[r*C + c] ----------------
__global__ void transpose_kernel(const float* __restrict__ src, float* __restrict__ dst,
                                 int R, int C) {
    int idx = blockIdx.x * 256 + threadIdx.x;
    if (idx < R * C) {
        int r = idx / C, c = idx % C;
        dst[c * R + r] = src[idx];
    }
}

// ---------------- QKV projection ----------------
// grid: B*L/16 = 512 blocks, block: 384 threads (one per output column)
__global__ void qkv_kernel(const float* __restrict__ h, const float* __restrict__ wT,
                           const float* __restrict__ bqkv,
                           float* __restrict__ qws, float* __restrict__ kws,
                           float* __restrict__ vws) {
    __shared__ __align__(16) float hs[16 * 128];
    const int tid = threadIdx.x;
    const int row0 = blockIdx.x * 16;
    for (int i = tid; i < 2048; i += 384) hs[i] = h[row0 * 128 + i];
    __syncthreads();

    const int c = tid;
    float acc[16];
#pragma unroll
    for (int r = 0; r < 16; ++r) acc[r] = 0.f;

    for (int d0 = 0; d0 < 128; d0 += 4) {
        float w0 = wT[(d0 + 0) * 384 + c];
        float w1 = wT[(d0 + 1) * 384 + c];
        float w2 = wT[(d0 + 2) * 384 + c];
        float w3 = wT[(d0 + 3) * 384 + c];
#pragma unroll
        for (int r = 0; r < 16; ++r) {
            float4 h4 = *reinterpret_cast<const float4*>(&hs[r * 128 + d0]);
            acc[r] = fmaf(w0, h4.x, acc[r]);
            acc[r] = fmaf(w1, h4.y, acc[r]);
            acc[r] = fmaf(w2, h4.z, acc[r]);
            acc[r] = fmaf(w3, h4.w, acc[r]);
        }
    }
    const int part = c >> 7;        // 0=q 1=k 2=v
    const int cc = c & 127;
    const int head = cc >> 5;
    const int dd = cc & 31;
    const float bias = bqkv[c];
    float* dstb = (part == 0) ? qws : ((part == 1) ? kws : vws);
    const float scale = (part == 0) ? 0.17677669529663687f : 1.0f; // 1/sqrt(32) folded into q
#pragma unroll
    for (int r = 0; r < 16; ++r) {
        int grow = row0 + r;
        int b = grow >> 11, l = grow & 2047;
        dstb[((b * 4 + head) * 2048 + l) * 32 + dd] = (acc[r] + bias) * scale;
    }
}

// ---------------- attention ----------------
// grid: B*H*(L/16) = 2048 blocks, block: 256 threads (4 waves, 4 q-rows per wave).
// Register-lean: per-q state halved vs R4, K in two dk-halves (kr[4]),
// sparse-mask packed to bits, V double-buffered in LDS (transient reg stage),
// one barrier per k-tile, bias/mask prefetched one tile ahead.
__global__ __launch_bounds__(256, 6) void attn_kernel(
        const float* __restrict__ qws, const float* __restrict__ kws,
        const float* __restrict__ vws, const float* __restrict__ bias,
        const unsigned char* __restrict__ sm8,
        const int* __restrict__ sm32,
        const int* __restrict__ smflag,
        const float* __restrict__ nmask, float* __restrict__ aout) {
    __shared__ __align__(16) float q_lds[16 * 32];        // 2 KB
    __shared__ __align__(16) float v_lds[2][64 * 32];     // 16 KB double-buffered
    __shared__ __align__(16) float p_lds[4][4 * 72];      // 4.5 KB, wave-private

    const int tid = threadIdx.x;
    const int w = tid >> 6;
    const int lane = tid & 63;
    // bijective XCD-chunk swizzle (2048 % 8 == 0): each XCD owns 2 bh's worth
    const int lb = (blockIdx.x & 7) * 256 + (blockIdx.x >> 3);
    const int bh = lb >> 7;           // b*4 + h
    const int qt = lb & 127;
    const int q0 = qt * 16;
    const int b = bh >> 2;
    const int hh = bh & 3;
    const int bytemode = *smflag;     // uniform scalar

    const float* kb = kws + (size_t)bh * 2048 * 32;
    const float4* vb4 = reinterpret_cast<const float4*>(vws + (size_t)bh * 2048 * 32);
    const int qbase = w * 4;               // wave's first local q-row
    const int d4 = lane & 7;               // float4 dim group (0..7)
    const int myq = (lane >> 3) & 3;       // lane's q-row for PV
    const int kh = lane >> 5;              // k-half (0: k 0..31, 1: k 32..63)
    const size_t biasrow = (size_t)(bh * 2048 + q0 + qbase) * 2048;
    const size_t maskrow = (size_t)(b * 2048 + q0 + qbase) * 2048;
    const float* nmb = nmask + b * 2048;

    // -------- prologue: stage Q + V tile 0; prefetch bias/mask tile 0 --------
    if (tid < 128)
        reinterpret_cast<float4*>(q_lds)[tid] =
            reinterpret_cast<const float4*>(qws + (size_t)(bh * 2048 + q0) * 32)[tid];
    {
        float4 a = vb4[tid], c2 = vb4[256 + tid];
        float4* vl = reinterpret_cast<float4*>(v_lds[0]);
        vl[tid] = a; vl[256 + tid] = c2;
    }
    float bv[4]; int mb; float keym;
    {
        keym = nmb[lane];
        int t = 0;
        if (bytemode) {
#pragma unroll
            for (int q = 0; q < 4; ++q) t |= (sm8[maskrow + (size_t)q * 2048 + lane] ? (1 << q) : 0);
        } else {
#pragma unroll
            for (int q = 0; q < 4; ++q) t |= (sm32[maskrow + (size_t)q * 2048 + lane] ? (1 << q) : 0);
        }
        mb = t;
#pragma unroll
        for (int q = 0; q < 4; ++q) bv[q] = bias[biasrow + (size_t)q * 2048 + lane];
    }
    __syncthreads();

    float m[4], lsum[4];
#pragma unroll
    for (int i = 0; i < 4; ++i) { m[i] = -3.0e38f; lsum[i] = 0.f; }
    float4 acc4 = make_float4(0.f, 0.f, 0.f, 0.f);

    for (int k0 = 0; k0 < 2048; k0 += 64) {
        const int cur = (k0 >> 6) & 1;
        const int k = k0 + lane;

        // ---- issue next V tile loads early (transient regs; latency hides under QK+softmax)
        const int k0n = k0 + 64;
        const int vbase = (k0n < 2048) ? k0n * 8 : 0;
        float4 vs0 = vb4[vbase + tid];
        float4 vs1 = vb4[vbase + 256 + tid];

        // ---- QK^T in two dk-halves (kr[4] = 16 VGPR) ----
        float s[4];
#pragma unroll
        for (int q = 0; q < 4; ++q) s[q] = 0.f;
        const float4* kp = reinterpret_cast<const float4*>(kb + (size_t)k * 32);
#pragma unroll
        for (int half = 0; half < 2; ++half) {
            float4 kr[4];
#pragma unroll
            for (int i = 0; i < 4; ++i) kr[i] = kp[half * 4 + i];
#pragma unroll
            for (int d0 = 0; d0 < 4; ++d0) {
                float4 k4 = kr[d0];
#pragma unroll
                for (int q = 0; q < 4; ++q) {
                    float4 q4 = *reinterpret_cast<const float4*>(
                        &q_lds[(qbase + q) * 32 + half * 16 + d0 * 4]);
                    s[q] = fmaf(q4.x, k4.x, s[q]);
                    s[q] = fmaf(q4.y, k4.y, s[q]);
                    s[q] = fmaf(q4.z, k4.z, s[q]);
                    s[q] = fmaf(q4.w, k4.w, s[q]);
                }
            }
        }

        // ---- consume prefetched bias/mask ----
#pragma unroll
        for (int q = 0; q < 4; ++q) {
            bool keep = ((mb >> q) & 1) && (keym > 0.f);
            s[q] = keep ? (s[q] + bv[q]) : NEG_INF;
        }

        // ---- prefetch next tile's bias/mask/keymask ----
        const int kn = (k0n < 2048) ? (k0n + lane) : lane;
        float bv2[4]; int mb2 = 0;
        const float keym2 = nmb[kn];
        if (bytemode) {
#pragma unroll
            for (int q = 0; q < 4; ++q) mb2 |= (sm8[maskrow + (size_t)q * 2048 + kn] ? (1 << q) : 0);
        } else {
#pragma unroll
            for (int q = 0; q < 4; ++q) mb2 |= (sm32[maskrow + (size_t)q * 2048 + kn] ? (1 << q) : 0);
        }
#pragma unroll
        for (int q = 0; q < 4; ++q) bv2[q] = bias[biasrow + (size_t)q * 2048 + kn];

        // ---- online softmax (4 q-rows, full-wave reductions) ----
        float fsel = 1.f;
        float* pb = p_lds[w];
#pragma unroll
        for (int q = 0; q < 4; ++q) {
            float tm = s[q];
#pragma unroll
            for (int off = 32; off > 0; off >>= 1) tm = fmaxf(tm, __shfl_xor(tm, off));
            float nm2 = fmaxf(m[q], tm);
            float fq = __expf(m[q] - nm2);
            m[q] = nm2;
            float pv = __expf(s[q] - nm2);
            float ts = pv;
#pragma unroll
            for (int off = 32; off > 0; off >>= 1) ts += __shfl_xor(ts, off);
            lsum[q] = lsum[q] * fq + ts;
            pb[q * 72 + lane] = pv;
            fsel = (q == myq) ? fq : fsel;
        }
        acc4.x *= fsel; acc4.y *= fsel; acc4.z *= fsel; acc4.w *= fsel;

        // ---- write-late: next V tile into the other buffer ----
        {
            float4* vl = reinterpret_cast<float4*>(v_lds[cur ^ 1]);
            vl[tid] = vs0; vl[256 + tid] = vs1;
        }

        // ---- PV: lane (kh, myq, d4); k-halves combined at epilogue ----
        const float* prow = &p_lds[w][myq * 72 + kh * 32];
        const float4* vl4 = reinterpret_cast<const float4*>(v_lds[cur]);
        const int kbase = kh * 32;
#pragma unroll
        for (int kg = 0; kg < 32; kg += 4) {
            float4 p4 = *reinterpret_cast<const float4*>(&prow[kg]);
            float4 v0 = vl4[(kbase + kg + 0) * 8 + d4];
            float4 v1 = vl4[(kbase + kg + 1) * 8 + d4];
            float4 v2 = vl4[(kbase + kg + 2) * 8 + d4];
            float4 v3 = vl4[(kbase + kg + 3) * 8 + d4];
            acc4.x = fmaf(p4.x, v0.x, acc4.x); acc4.y = fmaf(p4.x, v0.y, acc4.y);
            acc4.z = fmaf(p4.x, v0.z, acc4.z); acc4.w = fmaf(p4.x, v0.w, acc4.w);
            acc4.x = fmaf(p4.y, v1.x, acc4.x); acc4.y = fmaf(p4.y, v1.y, acc4.y);
            acc4.z = fmaf(p4.y, v1.z, acc4.z); acc4.w = fmaf(p4.y, v1.w, acc4.w);
            acc4.x = fmaf(p4.z, v2.x, acc4.x); acc4.y = fmaf(p4.z, v2.y, acc4.y);
            acc4.z = fmaf(p4.z, v2.z, acc4.z); acc4.w = fmaf(p4.z, v2.w, acc4.w);
            acc4.x = fmaf(p4.w, v3.x, acc4.x); acc4.y = fmaf(p4.w, v3.y, acc4.y);
            acc4.z = fmaf(p4.w, v3.z, acc4.z); acc4.w = fmaf(p4.w, v3.w, acc4.w);
        }

        __syncthreads();   // v_lds[cur^1] visible; all waves done with v_lds[cur]
        keym = keym2; mb = mb2;
#pragma unroll
        for (int q = 0; q < 4; ++q) bv[q] = bv2[q];
    }

    // epilogue: combine k-halves, normalize, apply query mask, float4 store
    acc4.x += __shfl_xor(acc4.x, 32);
    acc4.y += __shfl_xor(acc4.y, 32);
    acc4.z += __shfl_xor(acc4.z, 32);
    acc4.w += __shfl_xor(acc4.w, 32);
    if (kh == 0) {
        float lv = lsum[0];
        if (myq == 1) lv = lsum[1];
        if (myq == 2) lv = lsum[2];
        if (myq == 3) lv = lsum[3];
        const int qrow = q0 + qbase + myq;
        const float nmq = nmb[qrow];
        const float inv = (nmq > 0.f) ? (1.f / lv) : 0.f;
        float4 o = make_float4(acc4.x * inv, acc4.y * inv, acc4.z * inv, acc4.w * inv);
        reinterpret_cast<float4*>(aout)[(size_t)(b * 2048 + qrow) * 32 + hh * 8 + d4] = o;
    }
}

// ---------------- LN stats helper (16 rows x 128 cols in LDS) ----------------
__device__ __forceinline__ void ln_stats(const float* buf, float* mu_s, float* rs_s, int tid) {
    int row = tid >> 4, sl = tid & 15;
    float4 x0 = *reinterpret_cast<const float4*>(&buf[row * 128 + sl * 8]);
    float4 x1 = *reinterpret_cast<const float4*>(&buf[row * 128 + sl * 8 + 4]);
    float sum = x0.x + x0.y + x0.z + x0.w + x1.x + x1.y + x1.z + x1.w;
    float sq = x0.x * x0.x + x0.y * x0.y + x0.z * x0.z + x0.w * x0.w +
               x1.x * x1.x + x1.y * x1.y + x1.z * x1.z + x1.w * x1.w;
#pragma unroll
    for (int off = 8; off > 0; off >>= 1) {
        sum += __shfl_xor(sum, off);
        sq += __shfl_xor(sq, off);
    }
    if (sl == 0) {
        float mu = sum * (1.f / 128.f);
        float var = sq * (1.f / 128.f) - mu * mu;
        mu_s[row] = mu;
        rs_s[row] = rsqrtf(var + EPS);
    }
}

// ---------------- fused epilogue: out-proj + res + LN1 + FFN + res + LN2 + mask ----------------
// grid: B*L/16 = 512 blocks, block: 256 threads
__global__ void epilogue_kernel(const float* __restrict__ aout, const float* __restrict__ h,
                                const float* __restrict__ woutT, const float* __restrict__ bout,
                                const float* __restrict__ wff1T, const float* __restrict__ bff1,
                                const float* __restrict__ wff2T, const float* __restrict__ bff2,
                                const float* __restrict__ g1, const float* __restrict__ b1,
                                const float* __restrict__ g2, const float* __restrict__ b2,
                                const float* __restrict__ nmask, float* __restrict__ out) {
    __shared__ __align__(16) float A[16 * 128];
    __shared__ __align__(16) float Hb[16 * 128];
    __shared__ __align__(16) float F[16 * 256];
    __shared__ float mu_s[16], rs_s[16];

    const int tid = threadIdx.x;
    const int row0 = blockIdx.x * 16;
    for (int i = tid; i < 2048; i += 256) {
        A[i] = aout[row0 * 128 + i];
        Hb[i] = h[row0 * 128 + i];
    }
    __syncthreads();

    const int g = tid >> 7, c = tid & 127;

    // --- out-projection ---
    float acc[8];
#pragma unroll
    for (int r = 0; r < 8; ++r) acc[r] = 0.f;
    for (int d0 = 0; d0 < 128; d0 += 4) {
        float w0 = woutT[(d0 + 0) * 128 + c];
        float w1 = woutT[(d0 + 1) * 128 + c];
        float w2 = woutT[(d0 + 2) * 128 + c];
        float w3 = woutT[(d0 + 3) * 128 + c];
#pragma unroll
        for (int r = 0; r < 8; ++r) {
            float4 a4 = *reinterpret_cast<const float4*>(&A[(g * 8 + r) * 128 + d0]);
            acc[r] = fmaf(w0, a4.x, acc[r]);
            acc[r] = fmaf(w1, a4.y, acc[r]);
            acc[r] = fmaf(w2, a4.z, acc[r]);
            acc[r] = fmaf(w3, a4.w, acc[r]);
        }
    }
    float bo = bout[c];
#pragma unroll
    for (int r = 0; r < 8; ++r) {
        int row = g * 8 + r;
        Hb[row * 128 + c] += acc[r] + bo;   // h + attn_out
    }
    __syncthreads();

    ln_stats(Hb, mu_s, rs_s, tid);
    __syncthreads();
    float g1c = g1[c], b1c = b1[c];
#pragma unroll
    for (int r = 0; r < 8; ++r) {
        int row = g * 8 + r;
        float v = (Hb[row * 128 + c] - mu_s[row]) * rs_s[row] * g1c + b1c;
        Hb[row * 128 + c] = v;              // h1
    }
    __syncthreads();

    // --- FF1 + ReLU (thread owns ff column j = tid) ---
    {
        const int j = tid;
        float a2[16];
#pragma unroll
        for (int r = 0; r < 16; ++r) a2[r] = 0.f;
        for (int d0 = 0; d0 < 128; d0 += 4) {
            float w0 = wff1T[(d0 + 0) * 256 + j];
            float w1 = wff1T[(d0 + 1) * 256 + j];
            float w2 = wff1T[(d0 + 2) * 256 + j];
            float w3 = wff1T[(d0 + 3) * 256 + j];
#pragma unroll
            for (int r = 0; r < 16; ++r) {
                float4 h4 = *reinterpret_cast<const float4*>(&Hb[r * 128 + d0]);
                a2[r] = fmaf(w0, h4.x, a2[r]);
                a2[r] = fmaf(w1, h4.y, a2[r]);
                a2[r] = fmaf(w2, h4.z, a2[r]);
                a2[r] = fmaf(w3, h4.w, a2[r]);
            }
        }
        float bj = bff1[j];
#pragma unroll
        for (int r = 0; r < 16; ++r) F[r * 256 + j] = fmaxf(a2[r] + bj, 0.f);
    }
    __syncthreads();

    // --- FF2 + residual ---
    float a3[8];
#pragma unroll
    for (int r = 0; r < 8; ++r) a3[r] = 0.f;
    for (int d0 = 0; d0 < 256; d0 += 4) {
        float w0 = wff2T[(d0 + 0) * 128 + c];
        float w1 = wff2T[(d0 + 1) * 128 + c];
        float w2 = wff2T[(d0 + 2) * 128 + c];
        float w3 = wff2T[(d0 + 3) * 128 + c];
#pragma unroll
        for (int r = 0; r < 8; ++r) {
            float4 f4 = *reinterpret_cast<const float4*>(&F[(g * 8 + r) * 256 + d0]);
            a3[r] = fmaf(w0, f4.x, a3[r]);
            a3[r] = fmaf(w1, f4.y, a3[r]);
            a3[r] = fmaf(w2, f4.z, a3[r]);
            a3[r] = fmaf(w3, f4.w, a3[r]);
        }
    }
    float bo2 = bff2[c];
#pragma unroll
    for (int r = 0; r < 8; ++r) {
        int row = g * 8 + r;
        A[row * 128 + c] = a3[r] + bo2 + Hb[row * 128 + c];   // h1 + ff
    }
    __syncthreads();

    ln_stats(A, mu_s, rs_s, tid);
    __syncthreads();
    float g2c = g2[c], b2c = b2[c];
#pragma unroll
    for (int r = 0; r < 8; ++r) {
        int row = g * 8 + r;
        float nm = nmask[row0 + row];
        float v = (A[row * 128 + c] - mu_s[row]) * rs_s[row] * g2c + b2c;
        out[(row0 + row) * 128 + c] = v * nm;
    }
}

extern "C" void kernel_launch(void* const* d_in, const int* in_sizes, int n_in,
                              void* d_out, int out_size, void* d_ws, size_t ws_size,
                              hipStream_t stream) {
    const float* h = (const float*)d_in[0];
    const float* bias = (const float*)d_in[1];
    const float* nmask = (const float*)d_in[2];
    const void* smask = d_in[3];                 // bool -> byte or int32 (detected)
    const float* w_qkv = (const float*)d_in[4];
    const float* b_qkv = (const float*)d_in[5];
    const float* w_out = (const float*)d_in[6];
    const float* b_out = (const float*)d_in[7];
    const float* w_ff1 = (const float*)d_in[8];
    const float* b_ff1 = (const float*)d_in[9];
    const float* w_ff2 = (const float*)d_in[10];
    const float* b_ff2 = (const float*)d_in[11];
    const float* g1 = (const float*)d_in[12];
    const float* b1 = (const float*)d_in[13];
    const float* g2 = (const float*)d_in[14];
    const float* b2 = (const float*)d_in[15];
    float* out = (float*)d_out;

    float* ws = (float*)d_ws;
    float* qws = ws;                       // 1M floats
    float* kws = ws + (1 << 20);           // 1M
    float* vws = ws + 2 * (1 << 20);       // 1M
    float* aoutw = ws + 3 * (1 << 20);     // 1M
    float* wqkvT = ws + 4 * (1 << 20);     // 384*128
    float* woutT = wqkvT + 384 * 128;      // 128*128
    float* wff1T = woutT + 128 * 128;      // 256*128
    float* wff2T = wff1T + 256 * 128;      // 128*256
    int* smflag = (int*)(wff2T + 128 * 256);

    detect_mask_kernel<<<1, 256, 0, stream>>>((const unsigned int*)smask, smflag);
    transpose_kernel<<<192, 256, 0, stream>>>(w_qkv, wqkvT, 384, 128);
    transpose_kernel<<<64, 256, 0, stream>>>(w_out, woutT, 128, 128);
    transpose_kernel<<<128, 256, 0, stream>>>(w_ff1, wff1T, 256, 128);
    transpose_kernel<<<128, 256, 0, stream>>>(w_ff2, wff2T, 128, 256);
    qkv_kernel<<<512, 384, 0, stream>>>(h, wqkvT, b_qkv, qws, kws, vws);
    attn_kernel<<<2048, 256, 0, stream>>>(qws, kws, vws, bias,
                                          (const unsigned char*)smask, (const int*)smask,
                                          smflag, nmask, aoutw);
    epilogue_kernel<<<512, 256, 0, stream>>>(aoutw, h, woutT, b_out, wff1T, b_ff1,
                                             wff2T, b_ff2, g1, b1, g2, b2, nmask, out);
}

// Round 6
// 452.392 us; speedup vs baseline: 8.4029x; 8.4029x over previous
//
#include <hip/hip_runtime.h>
#include <math.h>

#define NEG_INF (-1e9f)
#define EPS 1e-5f

// async global->LDS, 16B per lane, zero VGPR cost.
// LDS dest is wave-uniform base + lane*16; global src is per-lane.
__device__ __forceinline__ void gl2lds16(const void* g, void* l) {
    __builtin_amdgcn_global_load_lds(
        (const __attribute__((address_space(1))) unsigned int*)g,
        (__attribute__((address_space(3))) unsigned int*)l, 16, 0, 0);
}

// ---------------- detect sparse_mask storage: int32 (0/1) vs packed bytes ----------------
__global__ void detect_mask_kernel(const unsigned int* __restrict__ sm, int* __restrict__ flag) {
    __shared__ int bad;
    if (threadIdx.x == 0) bad = 0;
    __syncthreads();
    for (int i = threadIdx.x; i < 4096; i += 256) {
        if (sm[i] > 1u) bad = 1;   // impossible for int32 bool storage
    }
    __syncthreads();
    if (threadIdx.x == 0) *flag = bad;   // 1 -> byte storage, 0 -> int32 storage
}

// ---------------- transpose: dst[c*R + r] = src[r*C + c] ----------------
__global__ void transpose_kernel(const float* __restrict__ src, float* __restrict__ dst,
                                 int R, int C) {
    int idx = blockIdx.x * 256 + threadIdx.x;
    if (idx < R * C) {
        int r = idx / C, c = idx % C;
        dst[c * R + r] = src[idx];
    }
}

// ---------------- QKV projection ----------------
// grid: B*L/16 = 512 blocks, block: 384 threads (one per output column)
__global__ void qkv_kernel(const float* __restrict__ h, const float* __restrict__ wT,
                           const float* __restrict__ bqkv,
                           float* __restrict__ qws, float* __restrict__ kws,
                           float* __restrict__ vws) {
    __shared__ __align__(16) float hs[16 * 128];
    const int tid = threadIdx.x;
    const int row0 = blockIdx.x * 16;
    for (int i = tid; i < 2048; i += 384) hs[i] = h[row0 * 128 + i];
    __syncthreads();

    const int c = tid;
    float acc[16];
#pragma unroll
    for (int r = 0; r < 16; ++r) acc[r] = 0.f;

    for (int d0 = 0; d0 < 128; d0 += 4) {
        float w0 = wT[(d0 + 0) * 384 + c];
        float w1 = wT[(d0 + 1) * 384 + c];
        float w2 = wT[(d0 + 2) * 384 + c];
        float w3 = wT[(d0 + 3) * 384 + c];
#pragma unroll
        for (int r = 0; r < 16; ++r) {
            float4 h4 = *reinterpret_cast<const float4*>(&hs[r * 128 + d0]);
            acc[r] = fmaf(w0, h4.x, acc[r]);
            acc[r] = fmaf(w1, h4.y, acc[r]);
            acc[r] = fmaf(w2, h4.z, acc[r]);
            acc[r] = fmaf(w3, h4.w, acc[r]);
        }
    }
    const int part = c >> 7;        // 0=q 1=k 2=v
    const int cc = c & 127;
    const int head = cc >> 5;
    const int dd = cc & 31;
    const float bias = bqkv[c];
    float* dstb = (part == 0) ? qws : ((part == 1) ? kws : vws);
    const float scale = (part == 0) ? 0.17677669529663687f : 1.0f; // 1/sqrt(32) folded into q
#pragma unroll
    for (int r = 0; r < 16; ++r) {
        int grow = row0 + r;
        int b = grow >> 11, l = grow & 2047;
        dstb[((b * 4 + head) * 2048 + l) * 32 + dd] = (acc[r] + bias) * scale;
    }
}

// ---------------- attention ----------------
// grid: B*H*(L/32) = 1024 blocks (exactly 4/CU resident), block: 256 threads.
// KTILE=32. V/bias/sparse-mask double-buffered in LDS via global_load_lds
// (async, zero VGPR). One barrier per k-tile (its vmcnt(0) drain flips buffers).
// Half-wave owns 4 q-rows: lanes 0-31 -> rows 0-3, lanes 32-63 -> rows 4-7.
// K read from global (L2-resident via XCD-chunk swizzle).
__global__ __launch_bounds__(256, 4) void attn_kernel(
        const float* __restrict__ qws, const float* __restrict__ kws,
        const float* __restrict__ vws, const float* __restrict__ bias,
        const unsigned char* __restrict__ sm8,
        const int* __restrict__ sm32,
        const int* __restrict__ smflag,
        const float* __restrict__ nmask, float* __restrict__ aout) {
    __shared__ __align__(16) float q_lds[32 * 32];         // 4 KB
    __shared__ __align__(16) float v_lds[2][32 * 32];      // 8 KB
    __shared__ __align__(16) float bias_lds[2][32 * 32];   // 8 KB
    __shared__ __align__(16) int   m32_lds[2][32 * 32];    // 8 KB (byte mode uses 1KB of it)
    __shared__ __align__(16) float p_lds[4][8 * 36];       // 4.6 KB, wave-private, pad 36

    const int tid = threadIdx.x;
    const int wq = tid >> 6;
    const int lane = tid & 63;
    // bijective XCD-chunk swizzle (1024 % 8 == 0): XCD owns 128 consecutive lb = 2 bh
    const int lb = (blockIdx.x & 7) * 128 + (blockIdx.x >> 3);
    const int bh = lb >> 6;           // b*4 + h
    const int qt = lb & 63;
    const int q0 = qt * 32;
    const int b = bh >> 2;
    const int hh = bh & 3;
    const int bytemode = *smflag;     // uniform scalar

    const float* kb = kws + (size_t)bh * 2048 * 32;
    const float* vbhp = vws + (size_t)bh * 2048 * 32;
    const int qbase = wq * 8;              // wave's first local q-row
    const int qh = lane >> 5;              // half: owns rows qh*4 .. qh*4+3
    const int kl = lane & 31;              // k within tile
    const int qp = lane >> 3;              // PV row (0..7); qp>>2 == qh always
    const int d4 = lane & 7;               // PV float4 dim group
    const float* nmb = nmask + b * 2048;

    // staging lane->address maps (16B/lane)
    const size_t bias_gbase = (size_t)(bh * 2048 + q0 + wq * 8 + (lane >> 3)) * 2048 + (lane & 7) * 4;
    const size_t m32_gbase  = (size_t)(b  * 2048 + q0 + wq * 8 + (lane >> 3)) * 2048 + (lane & 7) * 4;
    const size_t m8_gbase   = (size_t)(b  * 2048 + q0 + wq * 8 + (lane >> 1)) * 2048 + (lane & 1) * 16;

    auto stage = [&](int buf, int t) {
        const int k0 = t * 32;
        // V tile: 32 rows x 32 floats, contiguous 4KB; 1KB per wave
        gl2lds16(vbhp + (size_t)k0 * 32 + wq * 256 + lane * 4, &v_lds[buf][wq * 256]);
        // bias tile: 32 rows x 32 floats, row stride 2048
        gl2lds16(bias + bias_gbase + k0, &bias_lds[buf][wq * 256]);
        if (bytemode) {
            if (lane < 16)   // 1KB tile: 8 rows x 32B per wave, 16 lanes
                gl2lds16(sm8 + m8_gbase + k0,
                         (char*)&m32_lds[buf][0] + wq * 256);
        } else {
            gl2lds16(sm32 + m32_gbase + k0, &m32_lds[buf][wq * 256]);
        }
    };

    // -------- prologue: stage tile 0 + Q --------
    stage(0, 0);
    if (tid < 256) {
        reinterpret_cast<float4*>(q_lds)[tid] =
            reinterpret_cast<const float4*>(qws + (size_t)(bh * 2048 + q0) * 32)[tid];
    }
    __syncthreads();

    float m[4], lsum[4];
#pragma unroll
    for (int i = 0; i < 4; ++i) { m[i] = -3.0e38f; lsum[i] = 0.f; }
    float4 acc4 = make_float4(0.f, 0.f, 0.f, 0.f);

    for (int t = 0; t < 64; ++t) {
        const int cur = t & 1;
        if (t + 1 < 64) stage(cur ^ 1, t + 1);   // async into other buffer
        const int k0 = t * 32;
        const float keym = nmb[k0 + kl];         // tiny, L1-resident

        // ---- QK^T: 4 q-rows x 32 dims per lane, K in two register halves ----
        float s[4] = {0.f, 0.f, 0.f, 0.f};
        const float4* kp = reinterpret_cast<const float4*>(kb + (size_t)(k0 + kl) * 32);
#pragma unroll
        for (int half = 0; half < 2; ++half) {
            float4 kr[4];
#pragma unroll
            for (int i = 0; i < 4; ++i) kr[i] = kp[half * 4 + i];
#pragma unroll
            for (int d0 = 0; d0 < 4; ++d0) {
                float4 k4 = kr[d0];
#pragma unroll
                for (int qq = 0; qq < 4; ++qq) {
                    float4 q4 = *reinterpret_cast<const float4*>(
                        &q_lds[(qbase + qh * 4 + qq) * 32 + half * 16 + d0 * 4]);
                    s[qq] = fmaf(q4.x, k4.x, s[qq]);
                    s[qq] = fmaf(q4.y, k4.y, s[qq]);
                    s[qq] = fmaf(q4.z, k4.z, s[qq]);
                    s[qq] = fmaf(q4.w, k4.w, s[qq]);
                }
            }
        }

        // ---- bias + masks from LDS (staged last iteration) ----
        if (bytemode) {
            const unsigned char* m8l = (const unsigned char*)&m32_lds[cur][0];
#pragma unroll
            for (int qq = 0; qq < 4; ++qq) {
                const int row = qbase + qh * 4 + qq;
                bool keep = (m8l[row * 32 + kl] != 0) && (keym > 0.f);
                s[qq] = keep ? (s[qq] + bias_lds[cur][row * 32 + kl]) : NEG_INF;
            }
        } else {
#pragma unroll
            for (int qq = 0; qq < 4; ++qq) {
                const int row = qbase + qh * 4 + qq;
                bool keep = (m32_lds[cur][row * 32 + kl] != 0) && (keym > 0.f);
                s[qq] = keep ? (s[qq] + bias_lds[cur][row * 32 + kl]) : NEG_INF;
            }
        }

        // ---- online softmax per q-row (32-lane half reductions) ----
        float fq[4];
#pragma unroll
        for (int qq = 0; qq < 4; ++qq) {
            float tm = s[qq];
#pragma unroll
            for (int off = 16; off > 0; off >>= 1) tm = fmaxf(tm, __shfl_xor(tm, off));
            float nm2 = fmaxf(m[qq], tm);
            float f = __expf(m[qq] - nm2);
            m[qq] = nm2;
            float pv = __expf(s[qq] - nm2);
            float ts = pv;
#pragma unroll
            for (int off = 16; off > 0; off >>= 1) ts += __shfl_xor(ts, off);
            lsum[qq] = lsum[qq] * f + ts;
            fq[qq] = f;
            p_lds[wq][(qh * 4 + qq) * 36 + kl] = pv;
        }
        // rescale factor for this lane's PV row (qp is in own half: qp>>2==qh)
        float fm = fq[0];
        fm = ((qp & 3) == 1) ? fq[1] : fm;
        fm = ((qp & 3) == 2) ? fq[2] : fm;
        fm = ((qp & 3) == 3) ? fq[3] : fm;
        acc4.x *= fm; acc4.y *= fm; acc4.z *= fm; acc4.w *= fm;

        // ---- PV: lane (qp, d4); p wave-private, V broadcast float4 ----
        const float* prow = &p_lds[wq][qp * 36];
        const float4* vl = reinterpret_cast<const float4*>(&v_lds[cur][0]);
#pragma unroll
        for (int kg = 0; kg < 32; kg += 4) {
            float4 p4 = *reinterpret_cast<const float4*>(&prow[kg]);
            float4 v0 = vl[(kg + 0) * 8 + d4];
            float4 v1 = vl[(kg + 1) * 8 + d4];
            float4 v2 = vl[(kg + 2) * 8 + d4];
            float4 v3 = vl[(kg + 3) * 8 + d4];
            acc4.x = fmaf(p4.x, v0.x, acc4.x); acc4.y = fmaf(p4.x, v0.y, acc4.y);
            acc4.z = fmaf(p4.x, v0.z, acc4.z); acc4.w = fmaf(p4.x, v0.w, acc4.w);
            acc4.x = fmaf(p4.y, v1.x, acc4.x); acc4.y = fmaf(p4.y, v1.y, acc4.y);
            acc4.z = fmaf(p4.y, v1.z, acc4.z); acc4.w = fmaf(p4.y, v1.w, acc4.w);
            acc4.x = fmaf(p4.z, v2.x, acc4.x); acc4.y = fmaf(p4.z, v2.y, acc4.y);
            acc4.z = fmaf(p4.z, v2.z, acc4.z); acc4.w = fmaf(p4.z, v2.w, acc4.w);
            acc4.x = fmaf(p4.w, v3.x, acc4.x); acc4.y = fmaf(p4.w, v3.y, acc4.y);
            acc4.z = fmaf(p4.w, v3.z, acc4.z); acc4.w = fmaf(p4.w, v3.w, acc4.w);
        }

        __syncthreads();   // drains vmcnt: next tile staged; all waves done with buf cur
    }

    // ---- epilogue: normalize, query mask, float4 store ----
    float lv = lsum[0];
    lv = ((qp & 3) == 1) ? lsum[1] : lv;
    lv = ((qp & 3) == 2) ? lsum[2] : lv;
    lv = ((qp & 3) == 3) ? lsum[3] : lv;
    const int qrow = q0 + qbase + qp;
    const float nmq = nmb[qrow];
    const float inv = (nmq > 0.f) ? (1.f / lv) : 0.f;
    float4 o = make_float4(acc4.x * inv, acc4.y * inv, acc4.z * inv, acc4.w * inv);
    reinterpret_cast<float4*>(aout)[(size_t)(b * 2048 + qrow) * 32 + hh * 8 + d4] = o;
}

// ---------------- LN stats helper (16 rows x 128 cols in LDS) ----------------
__device__ __forceinline__ void ln_stats(const float* buf, float* mu_s, float* rs_s, int tid) {
    int row = tid >> 4, sl = tid & 15;
    float4 x0 = *reinterpret_cast<const float4*>(&buf[row * 128 + sl * 8]);
    float4 x1 = *reinterpret_cast<const float4*>(&buf[row * 128 + sl * 8 + 4]);
    float sum = x0.x + x0.y + x0.z + x0.w + x1.x + x1.y + x1.z + x1.w;
    float sq = x0.x * x0.x + x0.y * x0.y + x0.z * x0.z + x0.w * x0.w +
               x1.x * x1.x + x1.y * x1.y + x1.z * x1.z + x1.w * x1.w;
#pragma unroll
    for (int off = 8; off > 0; off >>= 1) {
        sum += __shfl_xor(sum, off);
        sq += __shfl_xor(sq, off);
    }
    if (sl == 0) {
        float mu = sum * (1.f / 128.f);
        float var = sq * (1.f / 128.f) - mu * mu;
        mu_s[row] = mu;
        rs_s[row] = rsqrtf(var + EPS);
    }
}

// ---------------- fused epilogue: out-proj + res + LN1 + FFN + res + LN2 + mask ----------------
// grid: B*L/16 = 512 blocks, block: 256 threads
__global__ void epilogue_kernel(const float* __restrict__ aout, const float* __restrict__ h,
                                const float* __restrict__ woutT, const float* __restrict__ bout,
                                const float* __restrict__ wff1T, const float* __restrict__ bff1,
                                const float* __restrict__ wff2T, const float* __restrict__ bff2,
                                const float* __restrict__ g1, const float* __restrict__ b1,
                                const float* __restrict__ g2, const float* __restrict__ b2,
                                const float* __restrict__ nmask, float* __restrict__ out) {
    __shared__ __align__(16) float A[16 * 128];
    __shared__ __align__(16) float Hb[16 * 128];
    __shared__ __align__(16) float F[16 * 256];
    __shared__ float mu_s[16], rs_s[16];

    const int tid = threadIdx.x;
    const int row0 = blockIdx.x * 16;
    for (int i = tid; i < 2048; i += 256) {
        A[i] = aout[row0 * 128 + i];
        Hb[i] = h[row0 * 128 + i];
    }
    __syncthreads();

    const int g = tid >> 7, c = tid & 127;

    // --- out-projection ---
    float acc[8];
#pragma unroll
    for (int r = 0; r < 8; ++r) acc[r] = 0.f;
    for (int d0 = 0; d0 < 128; d0 += 4) {
        float w0 = woutT[(d0 + 0) * 128 + c];
        float w1 = woutT[(d0 + 1) * 128 + c];
        float w2 = woutT[(d0 + 2) * 128 + c];
        float w3 = woutT[(d0 + 3) * 128 + c];
#pragma unroll
        for (int r = 0; r < 8; ++r) {
            float4 a4 = *reinterpret_cast<const float4*>(&A[(g * 8 + r) * 128 + d0]);
            acc[r] = fmaf(w0, a4.x, acc[r]);
            acc[r] = fmaf(w1, a4.y, acc[r]);
            acc[r] = fmaf(w2, a4.z, acc[r]);
            acc[r] = fmaf(w3, a4.w, acc[r]);
        }
    }
    float bo = bout[c];
#pragma unroll
    for (int r = 0; r < 8; ++r) {
        int row = g * 8 + r;
        Hb[row * 128 + c] += acc[r] + bo;   // h + attn_out
    }
    __syncthreads();

    ln_stats(Hb, mu_s, rs_s, tid);
    __syncthreads();
    float g1c = g1[c], b1c = b1[c];
#pragma unroll
    for (int r = 0; r < 8; ++r) {
        int row = g * 8 + r;
        float v = (Hb[row * 128 + c] - mu_s[row]) * rs_s[row] * g1c + b1c;
        Hb[row * 128 + c] = v;              // h1
    }
    __syncthreads();

    // --- FF1 + ReLU (thread owns ff column j = tid) ---
    {
        const int j = tid;
        float a2[16];
#pragma unroll
        for (int r = 0; r < 16; ++r) a2[r] = 0.f;
        for (int d0 = 0; d0 < 128; d0 += 4) {
            float w0 = wff1T[(d0 + 0) * 256 + j];
            float w1 = wff1T[(d0 + 1) * 256 + j];
            float w2 = wff1T[(d0 + 2) * 256 + j];
            float w3 = wff1T[(d0 + 3) * 256 + j];
#pragma unroll
            for (int r = 0; r < 16; ++r) {
                float4 h4 = *reinterpret_cast<const float4*>(&Hb[r * 128 + d0]);
                a2[r] = fmaf(w0, h4.x, a2[r]);
                a2[r] = fmaf(w1, h4.y, a2[r]);
                a2[r] = fmaf(w2, h4.z, a2[r]);
                a2[r] = fmaf(w3, h4.w, a2[r]);
            }
        }
        float bj = bff1[j];
#pragma unroll
        for (int r = 0; r < 16; ++r) F[r * 256 + j] = fmaxf(a2[r] + bj, 0.f);
    }
    __syncthreads();

    // --- FF2 + residual ---
    float a3[8];
#pragma unroll
    for (int r = 0; r < 8; ++r) a3[r] = 0.f;
    for (int d0 = 0; d0 < 256; d0 += 4) {
        float w0 = wff2T[(d0 + 0) * 128 + c];
        float w1 = wff2T[(d0 + 1) * 128 + c];
        float w2 = wff2T[(d0 + 2) * 128 + c];
        float w3 = wff2T[(d0 + 3) * 128 + c];
#pragma unroll
        for (int r = 0; r < 8; ++r) {
            float4 f4 = *reinterpret_cast<const float4*>(&F[(g * 8 + r) * 256 + d0]);
            a3[r] = fmaf(w0, f4.x, a3[r]);
            a3[r] = fmaf(w1, f4.y, a3[r]);
            a3[r] = fmaf(w2, f4.z, a3[r]);
            a3[r] = fmaf(w3, f4.w, a3[r]);
        }
    }
    float bo2 = bff2[c];
#pragma unroll
    for (int r = 0; r < 8; ++r) {
        int row = g * 8 + r;
        A[row * 128 + c] = a3[r] + bo2 + Hb[row * 128 + c];   // h1 + ff
    }
    __syncthreads();

    ln_stats(A, mu_s, rs_s, tid);
    __syncthreads();
    float g2c = g2[c], b2c = b2[c];
#pragma unroll
    for (int r = 0; r < 8; ++r) {
        int row = g * 8 + r;
        float nm = nmask[row0 + row];
        float v = (A[row * 128 + c] - mu_s[row]) * rs_s[row] * g2c + b2c;
        out[(row0 + row) * 128 + c] = v * nm;
    }
}

extern "C" void kernel_launch(void* const* d_in, const int* in_sizes, int n_in,
                              void* d_out, int out_size, void* d_ws, size_t ws_size,
                              hipStream_t stream) {
    const float* h = (const float*)d_in[0];
    const float* bias = (const float*)d_in[1];
    const float* nmask = (const float*)d_in[2];
    const void* smask = d_in[3];                 // bool -> byte or int32 (detected)
    const float* w_qkv = (const float*)d_in[4];
    const float* b_qkv = (const float*)d_in[5];
    const float* w_out = (const float*)d_in[6];
    const float* b_out = (const float*)d_in[7];
    const float* w_ff1 = (const float*)d_in[8];
    const float* b_ff1 = (const float*)d_in[9];
    const float* w_ff2 = (const float*)d_in[10];
    const float* b_ff2 = (const float*)d_in[11];
    const float* g1 = (const float*)d_in[12];
    const float* b1 = (const float*)d_in[13];
    const float* g2 = (const float*)d_in[14];
    const float* b2 = (const float*)d_in[15];
    float* out = (float*)d_out;

    float* ws = (float*)d_ws;
    float* qws = ws;                       // 1M floats
    float* kws = ws + (1 << 20);           // 1M
    float* vws = ws + 2 * (1 << 20);       // 1M
    float* aoutw = ws + 3 * (1 << 20);     // 1M
    float* wqkvT = ws + 4 * (1 << 20);     // 384*128
    float* woutT = wqkvT + 384 * 128;      // 128*128
    float* wff1T = woutT + 128 * 128;      // 256*128
    float* wff2T = wff1T + 256 * 128;      // 128*256
    int* smflag = (int*)(wff2T + 128 * 256);

    detect_mask_kernel<<<1, 256, 0, stream>>>((const unsigned int*)smask, smflag);
    transpose_kernel<<<192, 256, 0, stream>>>(w_qkv, wqkvT, 384, 128);
    transpose_kernel<<<64, 256, 0, stream>>>(w_out, woutT, 128, 128);
    transpose_kernel<<<128, 256, 0, stream>>>(w_ff1, wff1T, 256, 128);
    transpose_kernel<<<128, 256, 0, stream>>>(w_ff2, wff2T, 128, 256);
    qkv_kernel<<<512, 384, 0, stream>>>(h, wqkvT, b_qkv, qws, kws, vws);
    attn_kernel<<<1024, 256, 0, stream>>>(qws, kws, vws, bias,
                                          (const unsigned char*)smask, (const int*)smask,
                                          smflag, nmask, aoutw);
    epilogue_kernel<<<512, 256, 0, stream>>>(aoutw, h, woutT, b_out, wff1T, b_ff1,
                                             wff2T, b_ff2, g1, b1, g2, b2, nmask, out);
}

// Round 7
// 191.234 us; speedup vs baseline: 19.8784x; 2.3656x over previous
//
#include <hip/hip_runtime.h>
#include <math.h>

#define NEG_INF (-1e9f)
#define EPS 1e-5f

typedef __attribute__((ext_vector_type(8))) short short8;
typedef __attribute__((ext_vector_type(4))) float floatx4;

__device__ __forceinline__ unsigned short f2bf(float x) {
    union { float f; unsigned u; } v; v.f = x;
    unsigned r = v.u + 0x7fffu + ((v.u >> 16) & 1u);
    return (unsigned short)(r >> 16);
}

// ---------------- detect sparse_mask storage: int32 (0/1) vs packed bytes ----------------
__global__ void detect_mask_kernel(const unsigned int* __restrict__ sm, int* __restrict__ flag) {
    __shared__ int bad;
    if (threadIdx.x == 0) bad = 0;
    __syncthreads();
    for (int i = threadIdx.x; i < 4096; i += 256) {
        if (sm[i] > 1u) bad = 1;   // impossible for int32 bool storage
    }
    __syncthreads();
    if (threadIdx.x == 0) *flag = bad;   // 1 -> byte storage, 0 -> int32 storage
}

// ---------------- pack node_mask into bits: nmb[b][k/32] ----------------
__global__ void nmask_pack_kernel(const float* __restrict__ nm, unsigned int* __restrict__ nmb) {
    const int t = threadIdx.x;            // 256 = 4 b * 64 words
    const int b = t >> 6, w32 = t & 63;
    unsigned u = 0;
#pragma unroll
    for (int j = 0; j < 32; ++j)
        u |= (nm[b * 2048 + w32 * 32 + j] > 0.f ? 1u : 0u) << j;
    nmb[t] = u;
}

// ---------------- combined key-mask bits: cbits[(b*2048+q)*64 + k/32] ----------------
__global__ void mask_prep_kernel(const unsigned char* __restrict__ smraw,
                                 const int* __restrict__ flag,
                                 const unsigned int* __restrict__ nmb,
                                 unsigned int* __restrict__ cbits) {
    const int idx = blockIdx.x * 256 + threadIdx.x;   // 524288 total
    const int b = idx >> 17;
    const int q = (idx >> 6) & 2047;
    const int w32 = idx & 63;
    unsigned u = 0;
    if (*flag) {   // byte storage
        const uint4* p = reinterpret_cast<const uint4*>(
            smraw + (size_t)(b * 2048 + q) * 2048 + w32 * 32);
        uint4 a = p[0], c = p[1];
        unsigned wd0 = a.x, wd1 = a.y, wd2 = a.z, wd3 = a.w;
        unsigned wd4 = c.x, wd5 = c.y, wd6 = c.z, wd7 = c.w;
#define BYTES4(v, sh) \
        u |= ((v) & 0xffu ? 1u : 0u) << (sh); \
        u |= ((v) & 0xff00u ? 1u : 0u) << ((sh) + 1); \
        u |= ((v) & 0xff0000u ? 1u : 0u) << ((sh) + 2); \
        u |= ((v) & 0xff000000u ? 1u : 0u) << ((sh) + 3);
        BYTES4(wd0, 0) BYTES4(wd1, 4) BYTES4(wd2, 8) BYTES4(wd3, 12)
        BYTES4(wd4, 16) BYTES4(wd5, 20) BYTES4(wd6, 24) BYTES4(wd7, 28)
#undef BYTES4
    } else {       // int32 storage
        const uint4* p = reinterpret_cast<const uint4*>(
            reinterpret_cast<const unsigned int*>(smraw) + (size_t)(b * 2048 + q) * 2048 + w32 * 32);
#pragma unroll
        for (int wi = 0; wi < 8; ++wi) {
            uint4 a = p[wi];
            u |= (a.x ? 1u : 0u) << (wi * 4);
            u |= (a.y ? 1u : 0u) << (wi * 4 + 1);
            u |= (a.z ? 1u : 0u) << (wi * 4 + 2);
            u |= (a.w ? 1u : 0u) << (wi * 4 + 3);
        }
    }
    cbits[idx] = u & nmb[b * 64 + w32];
}

// ---------------- transpose: dst[c*R + r] = src[r*C + c] ----------------
__global__ void transpose_kernel(const float* __restrict__ src, float* __restrict__ dst,
                                 int R, int C) {
    int idx = blockIdx.x * 256 + threadIdx.x;
    if (idx < R * C) {
        int r = idx / C, c = idx % C;
        dst[c * R + r] = src[idx];
    }
}

// ---------------- QKV projection -> bf16 Q,K [bh][l][32]; bf16 V^T [bh][d][k] ----------------
// grid: B*L/16 = 512 blocks, block: 384 threads (one per output column)
__global__ void qkv_kernel(const float* __restrict__ h, const float* __restrict__ wT,
                           const float* __restrict__ bqkv,
                           unsigned short* __restrict__ qb, unsigned short* __restrict__ kbm,
                           unsigned short* __restrict__ vtb) {
    __shared__ __align__(16) float hs[16 * 128];
    const int tid = threadIdx.x;
    const int row0 = blockIdx.x * 16;
    for (int i = tid; i < 2048; i += 384) hs[i] = h[row0 * 128 + i];
    __syncthreads();

    const int c = tid;
    float acc[16];
#pragma unroll
    for (int r = 0; r < 16; ++r) acc[r] = 0.f;

    for (int d0 = 0; d0 < 128; d0 += 4) {
        float w0 = wT[(d0 + 0) * 384 + c];
        float w1 = wT[(d0 + 1) * 384 + c];
        float w2 = wT[(d0 + 2) * 384 + c];
        float w3 = wT[(d0 + 3) * 384 + c];
#pragma unroll
        for (int r = 0; r < 16; ++r) {
            float4 h4 = *reinterpret_cast<const float4*>(&hs[r * 128 + d0]);
            acc[r] = fmaf(w0, h4.x, acc[r]);
            acc[r] = fmaf(w1, h4.y, acc[r]);
            acc[r] = fmaf(w2, h4.z, acc[r]);
            acc[r] = fmaf(w3, h4.w, acc[r]);
        }
    }
    const int part = c >> 7;        // 0=q 1=k 2=v
    const int cc = c & 127;
    const int head = cc >> 5;
    const int dd = cc & 31;
    const float bias = bqkv[c];
    const float scale = (part == 0) ? 0.17677669529663687f : 1.0f; // 1/sqrt(32) into q
#pragma unroll
    for (int r = 0; r < 16; ++r) {
        int grow = row0 + r;
        int b = grow >> 11, l = grow & 2047;
        int bh = b * 4 + head;
        unsigned short val = f2bf((acc[r] + bias) * scale);
        if (part == 0)      qb[((size_t)bh * 2048 + l) * 32 + dd] = val;
        else if (part == 1) kbm[((size_t)bh * 2048 + l) * 32 + dd] = val;
        else                vtb[((size_t)bh * 32 + dd) * 2048 + l] = val;
    }
}

// ---------------- attention: bf16 MFMA, swapped operands, no block barriers ----------------
// grid: 512 blocks (XCD-swizzled), block: 256 threads = 4 independent waves.
// Wave owns 16 q-rows. Per 64-k tile: 4 QK mfma + 4 PV mfma.
// Lane (q=L&15, g=L>>4): QK gives 16 scores of row q (k = 16m+4g+reg);
// softmax = 15 in-lane ops + 2 shfl; P staged via wave-private LDS (pad 72);
// PV B-frag read back as 8 consecutive bf16; V^T A-frag straight from global bf16.
__global__ __launch_bounds__(256, 2) void attn_kernel(
        const unsigned short* __restrict__ qb, const unsigned short* __restrict__ kbm,
        const unsigned short* __restrict__ vtb, const float* __restrict__ bias,
        const unsigned int* __restrict__ cbits, const float* __restrict__ nmask,
        float* __restrict__ aout) {
    __shared__ unsigned short p_lds[4][16 * 72];   // 9216 B, wave-private rows

    const int tid = threadIdx.x;
    const int w = tid >> 6, L = tid & 63;
    const int lb = (blockIdx.x & 7) * 64 + (blockIdx.x >> 3);   // bijective, 512%8==0
    const int bh = lb >> 5, qt = lb & 31;
    const int b = bh >> 2, hh = bh & 3;
    const int q0 = qt * 64 + w * 16;
    const int q = L & 15, g = L >> 4;

    const unsigned short* kbase = kbm + (size_t)bh * 2048 * 32 + g * 8;
    const unsigned short* vbase = vtb + (size_t)bh * 32 * 2048 + g * 8;
    const short8 qf = *reinterpret_cast<const short8*>(
        qb + ((size_t)bh * 2048 + q0 + q) * 32 + g * 8);
    const float* brow = bias + ((size_t)bh * 2048 + q0 + q) * 2048 + g * 4;
    const unsigned int* crow = cbits + (size_t)(b * 2048 + q0 + q) * 64;

    float mrun = -3.0e38f, lrun = 0.f;
    floatx4 o0 = {0.f, 0.f, 0.f, 0.f}, o1 = {0.f, 0.f, 0.f, 0.f};
    const floatx4 zacc = {0.f, 0.f, 0.f, 0.f};
    unsigned short* pl = &p_lds[w][q * 72];

    for (int t = 0; t < 32; ++t) {
        const int k0 = t * 64;
        // ---- A-fragments of K (4 x 16B, each instr = contiguous 1KB per wave) ----
        short8 kf0 = *reinterpret_cast<const short8*>(kbase + (size_t)(k0 +  0 + q) * 32);
        short8 kf1 = *reinterpret_cast<const short8*>(kbase + (size_t)(k0 + 16 + q) * 32);
        short8 kf2 = *reinterpret_cast<const short8*>(kbase + (size_t)(k0 + 32 + q) * 32);
        short8 kf3 = *reinterpret_cast<const short8*>(kbase + (size_t)(k0 + 48 + q) * 32);
        // ---- bias (4 x float4 per lane; a row's 4 k-groups cover 256B contiguous) ----
        float4 bq0 = *reinterpret_cast<const float4*>(brow + k0);
        float4 bq1 = *reinterpret_cast<const float4*>(brow + k0 + 16);
        float4 bq2 = *reinterpret_cast<const float4*>(brow + k0 + 32);
        float4 bq3 = *reinterpret_cast<const float4*>(brow + k0 + 48);
        uint2 cw = *reinterpret_cast<const uint2*>(crow + t * 2);
        // ---- A-fragments of V^T ----
        short8 vf00 = *reinterpret_cast<const short8*>(vbase + (size_t)(q     ) * 2048 + k0);
        short8 vf01 = *reinterpret_cast<const short8*>(vbase + (size_t)(q     ) * 2048 + k0 + 32);
        short8 vf10 = *reinterpret_cast<const short8*>(vbase + (size_t)(16 + q) * 2048 + k0);
        short8 vf11 = *reinterpret_cast<const short8*>(vbase + (size_t)(16 + q) * 2048 + k0 + 32);

        // ---- QK^T ----
        float s[16];
        {
            floatx4 r0 = __builtin_amdgcn_mfma_f32_16x16x32_bf16(kf0, qf, zacc, 0, 0, 0);
            floatx4 r1 = __builtin_amdgcn_mfma_f32_16x16x32_bf16(kf1, qf, zacc, 0, 0, 0);
            floatx4 r2 = __builtin_amdgcn_mfma_f32_16x16x32_bf16(kf2, qf, zacc, 0, 0, 0);
            floatx4 r3 = __builtin_amdgcn_mfma_f32_16x16x32_bf16(kf3, qf, zacc, 0, 0, 0);
            s[0] = r0[0]; s[1] = r0[1]; s[2] = r0[2]; s[3] = r0[3];
            s[4] = r1[0]; s[5] = r1[1]; s[6] = r1[2]; s[7] = r1[3];
            s[8] = r2[0]; s[9] = r2[1]; s[10] = r2[2]; s[11] = r2[3];
            s[12] = r3[0]; s[13] = r3[1]; s[14] = r3[2]; s[15] = r3[3];
        }
        // ---- bias + combined mask (k = 16*mm + 4*g + reg) ----
        float bvv[16];
        bvv[0] = bq0.x; bvv[1] = bq0.y; bvv[2] = bq0.z; bvv[3] = bq0.w;
        bvv[4] = bq1.x; bvv[5] = bq1.y; bvv[6] = bq1.z; bvv[7] = bq1.w;
        bvv[8] = bq2.x; bvv[9] = bq2.y; bvv[10] = bq2.z; bvv[11] = bq2.w;
        bvv[12] = bq3.x; bvv[13] = bq3.y; bvv[14] = bq3.z; bvv[15] = bq3.w;
#pragma unroll
        for (int i = 0; i < 16; ++i) {
            const int mm = i >> 2, reg = i & 3;
            const unsigned word = (mm < 2) ? cw.x : cw.y;
            const int sh = 16 * (mm & 1) + 4 * g + reg;
            const bool keep = (word >> sh) & 1;
            s[i] = keep ? (s[i] + bvv[i]) : NEG_INF;
        }
        // ---- online softmax (in-lane 16 + 2 shfl) ----
        float tm = s[0];
#pragma unroll
        for (int i = 1; i < 16; ++i) tm = fmaxf(tm, s[i]);
        tm = fmaxf(tm, __shfl_xor(tm, 16));
        tm = fmaxf(tm, __shfl_xor(tm, 32));
        const float mn = fmaxf(mrun, tm);
        const float f = __expf(mrun - mn);
        mrun = mn;
        float p[16], ts = 0.f;
#pragma unroll
        for (int i = 0; i < 16; ++i) { p[i] = __expf(s[i] - mn); ts += p[i]; }
        ts += __shfl_xor(ts, 16);
        ts += __shfl_xor(ts, 32);
        lrun = lrun * f + ts;
        o0 *= f; o1 *= f;
        // ---- pack P -> bf16, stage in wave-private LDS row (stride 72) ----
#pragma unroll
        for (int mm = 0; mm < 4; ++mm) {
            unsigned u0 = (unsigned)f2bf(p[4 * mm]) | ((unsigned)f2bf(p[4 * mm + 1]) << 16);
            unsigned u1 = (unsigned)f2bf(p[4 * mm + 2]) | ((unsigned)f2bf(p[4 * mm + 3]) << 16);
            *reinterpret_cast<unsigned int*>(pl + 16 * mm + 4 * g) = u0;
            *reinterpret_cast<unsigned int*>(pl + 16 * mm + 4 * g + 2) = u1;
        }
        // ---- PV: B-frag = own row's 8 consecutive k ----
        short8 pb0 = *reinterpret_cast<const short8*>(pl + g * 8);
        short8 pb1 = *reinterpret_cast<const short8*>(pl + 32 + g * 8);
        o0 = __builtin_amdgcn_mfma_f32_16x16x32_bf16(vf00, pb0, o0, 0, 0, 0);
        o0 = __builtin_amdgcn_mfma_f32_16x16x32_bf16(vf01, pb1, o0, 0, 0, 0);
        o1 = __builtin_amdgcn_mfma_f32_16x16x32_bf16(vf10, pb0, o1, 0, 0, 0);
        o1 = __builtin_amdgcn_mfma_f32_16x16x32_bf16(vf11, pb1, o1, 0, 0, 0);
    }

    // ---- epilogue: normalize, query mask, write (lane: q-row q, dims g*4 & 16+g*4) ----
    const int qrow = q0 + q;
    const float nmq = nmask[b * 2048 + qrow];
    const float inv = (nmq > 0.f) ? (1.f / lrun) : 0.f;
    float* op = aout + ((size_t)b * 2048 + qrow) * 128 + hh * 32 + g * 4;
    *reinterpret_cast<float4*>(op) = make_float4(o0[0] * inv, o0[1] * inv, o0[2] * inv, o0[3] * inv);
    *reinterpret_cast<float4*>(op + 16) = make_float4(o1[0] * inv, o1[1] * inv, o1[2] * inv, o1[3] * inv);
}

// ---------------- LN stats helper (16 rows x 128 cols in LDS) ----------------
__device__ __forceinline__ void ln_stats(const float* buf, float* mu_s, float* rs_s, int tid) {
    int row = tid >> 4, sl = tid & 15;
    float4 x0 = *reinterpret_cast<const float4*>(&buf[row * 128 + sl * 8]);
    float4 x1 = *reinterpret_cast<const float4*>(&buf[row * 128 + sl * 8 + 4]);
    float sum = x0.x + x0.y + x0.z + x0.w + x1.x + x1.y + x1.z + x1.w;
    float sq = x0.x * x0.x + x0.y * x0.y + x0.z * x0.z + x0.w * x0.w +
               x1.x * x1.x + x1.y * x1.y + x1.z * x1.z + x1.w * x1.w;
#pragma unroll
    for (int off = 8; off > 0; off >>= 1) {
        sum += __shfl_xor(sum, off);
        sq += __shfl_xor(sq, off);
    }
    if (sl == 0) {
        float mu = sum * (1.f / 128.f);
        float var = sq * (1.f / 128.f) - mu * mu;
        mu_s[row] = mu;
        rs_s[row] = rsqrtf(var + EPS);
    }
}

// ---------------- fused epilogue: out-proj + res + LN1 + FFN + res + LN2 + mask ----------------
// grid: B*L/16 = 512 blocks, block: 256 threads
__global__ void epilogue_kernel(const float* __restrict__ aout, const float* __restrict__ h,
                                const float* __restrict__ woutT, const float* __restrict__ bout,
                                const float* __restrict__ wff1T, const float* __restrict__ bff1,
                                const float* __restrict__ wff2T, const float* __restrict__ bff2,
                                const float* __restrict__ g1, const float* __restrict__ b1,
                                const float* __restrict__ g2, const float* __restrict__ b2,
                                const float* __restrict__ nmask, float* __restrict__ out) {
    __shared__ __align__(16) float A[16 * 128];
    __shared__ __align__(16) float Hb[16 * 128];
    __shared__ __align__(16) float F[16 * 256];
    __shared__ float mu_s[16], rs_s[16];

    const int tid = threadIdx.x;
    const int row0 = blockIdx.x * 16;
    for (int i = tid; i < 2048; i += 256) {
        A[i] = aout[row0 * 128 + i];
        Hb[i] = h[row0 * 128 + i];
    }
    __syncthreads();

    const int g = tid >> 7, c = tid & 127;

    // --- out-projection ---
    float acc[8];
#pragma unroll
    for (int r = 0; r < 8; ++r) acc[r] = 0.f;
    for (int d0 = 0; d0 < 128; d0 += 4) {
        float w0 = woutT[(d0 + 0) * 128 + c];
        float w1 = woutT[(d0 + 1) * 128 + c];
        float w2 = woutT[(d0 + 2) * 128 + c];
        float w3 = woutT[(d0 + 3) * 128 + c];
#pragma unroll
        for (int r = 0; r < 8; ++r) {
            float4 a4 = *reinterpret_cast<const float4*>(&A[(g * 8 + r) * 128 + d0]);
            acc[r] = fmaf(w0, a4.x, acc[r]);
            acc[r] = fmaf(w1, a4.y, acc[r]);
            acc[r] = fmaf(w2, a4.z, acc[r]);
            acc[r] = fmaf(w3, a4.w, acc[r]);
        }
    }
    float bo = bout[c];
#pragma unroll
    for (int r = 0; r < 8; ++r) {
        int row = g * 8 + r;
        Hb[row * 128 + c] += acc[r] + bo;   // h + attn_out
    }
    __syncthreads();

    ln_stats(Hb, mu_s, rs_s, tid);
    __syncthreads();
    float g1c = g1[c], b1c = b1[c];
#pragma unroll
    for (int r = 0; r < 8; ++r) {
        int row = g * 8 + r;
        float v = (Hb[row * 128 + c] - mu_s[row]) * rs_s[row] * g1c + b1c;
        Hb[row * 128 + c] = v;              // h1
    }
    __syncthreads();

    // --- FF1 + ReLU (thread owns ff column j = tid) ---
    {
        const int j = tid;
        float a2[16];
#pragma unroll
        for (int r = 0; r < 16; ++r) a2[r] = 0.f;
        for (int d0 = 0; d0 < 128; d0 += 4) {
            float w0 = wff1T[(d0 + 0) * 256 + j];
            float w1 = wff1T[(d0 + 1) * 256 + j];
            float w2 = wff1T[(d0 + 2) * 256 + j];
            float w3 = wff1T[(d0 + 3) * 256 + j];
#pragma unroll
            for (int r = 0; r < 16; ++r) {
                float4 h4 = *reinterpret_cast<const float4*>(&Hb[r * 128 + d0]);
                a2[r] = fmaf(w0, h4.x, a2[r]);
                a2[r] = fmaf(w1, h4.y, a2[r]);
                a2[r] = fmaf(w2, h4.z, a2[r]);
                a2[r] = fmaf(w3, h4.w, a2[r]);
            }
        }
        float bj = bff1[j];
#pragma unroll
        for (int r = 0; r < 16; ++r) F[r * 256 + j] = fmaxf(a2[r] + bj, 0.f);
    }
    __syncthreads();

    // --- FF2 + residual ---
    float a3[8];
#pragma unroll
    for (int r = 0; r < 8; ++r) a3[r] = 0.f;
    for (int d0 = 0; d0 < 256; d0 += 4) {
        float w0 = wff2T[(d0 + 0) * 128 + c];
        float w1 = wff2T[(d0 + 1) * 128 + c];
        float w2 = wff2T[(d0 + 2) * 128 + c];
        float w3 = wff2T[(d0 + 3) * 128 + c];
#pragma unroll
        for (int r = 0; r < 8; ++r) {
            float4 f4 = *reinterpret_cast<const float4*>(&F[(g * 8 + r) * 256 + d0]);
            a3[r] = fmaf(w0, f4.x, a3[r]);
            a3[r] = fmaf(w1, f4.y, a3[r]);
            a3[r] = fmaf(w2, f4.z, a3[r]);
            a3[r] = fmaf(w3, f4.w, a3[r]);
        }
    }
    float bo2 = bff2[c];
#pragma unroll
    for (int r = 0; r < 8; ++r) {
        int row = g * 8 + r;
        A[row * 128 + c] = a3[r] + bo2 + Hb[row * 128 + c];   // h1 + ff
    }
    __syncthreads();

    ln_stats(A, mu_s, rs_s, tid);
    __syncthreads();
    float g2c = g2[c], b2c = b2[c];
#pragma unroll
    for (int r = 0; r < 8; ++r) {
        int row = g * 8 + r;
        float nm = nmask[row0 + row];
        float v = (A[row * 128 + c] - mu_s[row]) * rs_s[row] * g2c + b2c;
        out[(row0 + row) * 128 + c] = v * nm;
    }
}

extern "C" void kernel_launch(void* const* d_in, const int* in_sizes, int n_in,
                              void* d_out, int out_size, void* d_ws, size_t ws_size,
                              hipStream_t stream) {
    const float* h = (const float*)d_in[0];
    const float* bias = (const float*)d_in[1];
    const float* nmask = (const float*)d_in[2];
    const void* smask = d_in[3];                 // bool -> byte or int32 (detected)
    const float* w_qkv = (const float*)d_in[4];
    const float* b_qkv = (const float*)d_in[5];
    const float* w_out = (const float*)d_in[6];
    const float* b_out = (const float*)d_in[7];
    const float* w_ff1 = (const float*)d_in[8];
    const float* b_ff1 = (const float*)d_in[9];
    const float* w_ff2 = (const float*)d_in[10];
    const float* b_ff2 = (const float*)d_in[11];
    const float* g1 = (const float*)d_in[12];
    const float* b1 = (const float*)d_in[13];
    const float* g2 = (const float*)d_in[14];
    const float* b2 = (const float*)d_in[15];
    float* out = (float*)d_out;

    char* wsb = (char*)d_ws;
    float* aoutw = (float*)wsb;                               // 4 MB
    unsigned short* qb  = (unsigned short*)(wsb + (4 << 20)); // 2 MB
    unsigned short* kbm = (unsigned short*)(wsb + (6 << 20)); // 2 MB
    unsigned short* vtb = (unsigned short*)(wsb + (8 << 20)); // 2 MB
    unsigned int* cbits = (unsigned int*)(wsb + (10 << 20));  // 2 MB
    unsigned int* nmb   = (unsigned int*)(wsb + (12 << 20));  // 1 KB
    float* wqkvT = (float*)(wsb + (12 << 20) + 4096);         // 192 KB
    float* woutT = wqkvT + 384 * 128;
    float* wff1T = woutT + 128 * 128;
    float* wff2T = wff1T + 256 * 128;
    int* smflag = (int*)(wff2T + 128 * 256);

    detect_mask_kernel<<<1, 256, 0, stream>>>((const unsigned int*)smask, smflag);
    nmask_pack_kernel<<<1, 256, 0, stream>>>(nmask, nmb);
    mask_prep_kernel<<<2048, 256, 0, stream>>>((const unsigned char*)smask, smflag, nmb, cbits);
    transpose_kernel<<<192, 256, 0, stream>>>(w_qkv, wqkvT, 384, 128);
    transpose_kernel<<<64, 256, 0, stream>>>(w_out, woutT, 128, 128);
    transpose_kernel<<<128, 256, 0, stream>>>(w_ff1, wff1T, 256, 128);
    transpose_kernel<<<128, 256, 0, stream>>>(w_ff2, wff2T, 128, 256);
    qkv_kernel<<<512, 384, 0, stream>>>(h, wqkvT, b_qkv, qb, kbm, vtb);
    attn_kernel<<<512, 256, 0, stream>>>(qb, kbm, vtb, bias, cbits, nmask, aoutw);
    epilogue_kernel<<<512, 256, 0, stream>>>(aoutw, h, woutT, b_out, wff1T, b_ff1,
                                             wff2T, b_ff2, g1, b1, g2, b2, nmask, out);
}